// Round 1
// 626.075 us; speedup vs baseline: 1.1925x; 1.1925x over previous
//
#include <hip/hip_runtime.h>
#include <cstdint>

#define B_ 2
#define S_ 2048
#define D_ 768
#define H_ 12
#define DH_ 64
#define N_ 128

typedef unsigned short u16;
typedef unsigned int u32;
typedef __attribute__((ext_vector_type(8))) short short8;
typedef __attribute__((ext_vector_type(4))) float f32x4;

#define MFMA16(a, b, c) __builtin_amdgcn_mfma_f32_16x16x32_bf16(a, b, c, 0, 0, 0)

__device__ inline u16 f2bf(float f) {
  union { float f; u32 u; } v; v.f = f;
  u32 r = v.u + 0x7FFFu + ((v.u >> 16) & 1u);
  return (u16)(r >> 16);
}
__device__ inline u32 pk2(float a, float b) {
  return (u32)f2bf(a) | ((u32)f2bf(b) << 16);
}
__device__ inline float wredmax(float v) {
  #pragma unroll
  for (int o = 32; o > 0; o >>= 1) v = fmaxf(v, __shfl_down(v, o));
  return v;
}
__device__ inline float wredsum(float v) {
  #pragma unroll
  for (int o = 32; o > 0; o >>= 1) v += __shfl_down(v, o);
  return v;
}
__device__ inline void async_lds16(const u16* g, u16* l) {
  __builtin_amdgcn_global_load_lds((const __attribute__((address_space(1))) void*)g,
                                   (__attribute__((address_space(3))) void*)l, 16, 0, 0);
}

// ---------------- fp32 -> bf16 conversion, 8 elems/thread ----------------
__global__ void conv_bf16(const float* __restrict__ in, u16* __restrict__ outp, int n8) {
  int i = blockIdx.x * 256 + threadIdx.x;
  if (i >= n8) return;
  const float4* p = (const float4*)(in + (size_t)i * 8);
  float4 a = p[0], b = p[1];
  uint4 u;
  u.x = pk2(a.x, a.y); u.y = pk2(a.z, a.w); u.z = pk2(b.x, b.y); u.w = pk2(b.z, b.w);
  *(uint4*)(outp + (size_t)i * 8) = u;
}

// ================= pure-bf16 MFMA GEMM: C = A[M,K] @ W[N,K]^T + bias =================
template <int OUT_BF16>
__global__ __launch_bounds__(256) void gemm_bf16(
    const u16* __restrict__ A, int lda,
    const u16* __restrict__ W, int ldb,
    const float* __restrict__ bias,
    void* __restrict__ Cout, int ldc, int K) {
  __shared__ u16 As[128 * 32];
  __shared__ u16 Ws[128 * 32];
  const int tid = threadIdx.x;
  const int m0 = blockIdx.y * 128, n0 = blockIdx.x * 128;
  const int w = tid >> 6, lane = tid & 63;
  const int msub = (w & 1) * 64, nsub = (w >> 1) * 64;
  const int lrow = lane & 15, quad = lane >> 4;
  const int e0 = tid * 8;
  const int r0 = e0 >> 5, c0 = e0 & 31;
  const int e1 = e0 + 2048;
  const int r1 = e1 >> 5, c1 = e1 & 31;
  const u16* Ag0 = A + (size_t)(m0 + r0) * lda + c0;
  const u16* Ag1 = A + (size_t)(m0 + r1) * lda + c1;
  const u16* Wg0 = W + (size_t)(n0 + r0) * ldb + c0;
  const u16* Wg1 = W + (size_t)(n0 + r1) * ldb + c1;
  u16* AsB0 = As + (w << 9);
  u16* AsB1 = As + 2048 + (w << 9);
  u16* WsB0 = Ws + (w << 9);
  u16* WsB1 = Ws + 2048 + (w << 9);
  f32x4 zero = {0.f, 0.f, 0.f, 0.f};
  f32x4 acc[4][4];
  #pragma unroll
  for (int i = 0; i < 4; i++)
    #pragma unroll
    for (int j = 0; j < 4; j++) acc[i][j] = zero;
  for (int k0 = 0; k0 < K; k0 += 32) {
    __syncthreads();
    async_lds16(Ag0 + k0, AsB0);
    async_lds16(Ag1 + k0, AsB1);
    async_lds16(Wg0 + k0, WsB0);
    async_lds16(Wg1 + k0, WsB1);
    __syncthreads();
    short8 af[4], bf[4];
    #pragma unroll
    for (int i = 0; i < 4; i++)
      af[i] = *(const short8*)(As + (msub + i * 16 + lrow) * 32 + quad * 8);
    #pragma unroll
    for (int j = 0; j < 4; j++)
      bf[j] = *(const short8*)(Ws + (nsub + j * 16 + lrow) * 32 + quad * 8);
    #pragma unroll
    for (int i = 0; i < 4; i++)
      #pragma unroll
      for (int j = 0; j < 4; j++)
        acc[i][j] = MFMA16(af[i], bf[j], acc[i][j]);
  }
  #pragma unroll
  for (int i = 0; i < 4; i++) {
    #pragma unroll
    for (int j = 0; j < 4; j++) {
      int col = n0 + nsub + j * 16 + lrow;
      float bv = bias ? bias[col] : 0.f;
      #pragma unroll
      for (int r = 0; r < 4; r++) {
        int row = m0 + msub + i * 16 + quad * 4 + r;
        float val = acc[i][j][r] + bv;
        if (OUT_BF16) ((u16*)Cout)[(size_t)row * ldc + col] = f2bf(val);
        else ((float*)Cout)[(size_t)row * ldc + col] = val;
      }
    }
  }
}

// ================= V transpose: VT[b*12+h][d][s] = qkv[b][s][1536+h*64+d] =================
__global__ __launch_bounds__(256) void transpose_v(const u16* __restrict__ qkv, u16* __restrict__ VT) {
  __shared__ u16 t[64][72];
  const int z = blockIdx.y, b = z / 12, h = z - b * 12;
  const int s0 = blockIdx.x * 64;
  const int tid = threadIdx.x;
  {
    int r = tid >> 2, dp = (tid & 3) * 16;
    const u16* src = qkv + (size_t)b * 2048 * 2304 + (size_t)(s0 + r) * 2304 + 1536 + h * 64 + dp;
    *(uint4*)&t[r][dp] = *(const uint4*)src;
    *(uint4*)&t[r][dp + 8] = *(const uint4*)(src + 8);
  }
  __syncthreads();
  int d = tid >> 2, sp = (tid & 3) * 16;
  u16 vals[16];
  #pragma unroll
  for (int i = 0; i < 16; i++) vals[i] = t[sp + i][d];
  u16* dst = VT + ((size_t)z * 64 + d) * 2048 + s0 + sp;
  *(uint4*)dst = *(uint4*)&vals[0];
  *(uint4*)(dst + 8) = *(uint4*)&vals[8];
}

// ================= fused token attention (v4) =================
// grid: B*128 blocks (16 q-rows each), 512 threads = 8 waves (256-col strips).
// v4 changes vs v3:
//  - pass A keeps exp(s/8) in registers (f32x4 pex[16], fully unrolled -> static
//    indexing, no scratch). Pass C no longer re-loads K / re-runs QK MFMA / re-exps.
//  - global float atomicAdd output (25M atomic lane-ops) replaced by per-head LDS
//    partial tile obuf[8][16][66] (+2 pad cols -> <=2-way banks) + tree reduce,
//    storing bf16 DIRECTLY (kills the memset + conv_bf16 follow-up kernels).
//  - V tiles loaded before the P pack/LDS-write so global latency overlaps VALU.
// __launch_bounds__(512,2): 256-VGPR cap; est. live set ~190 (amreg 64 + pex 64 +
// oacc 16 + vf 32 + addressing). Grid = 256 = 1 block/CU.
__global__ __launch_bounds__(512, 2) void fused_tok_attn(
    const u16* __restrict__ qkv, const u16* __restrict__ VT,
    float* __restrict__ am, u16* __restrict__ attnout) {
  __shared__ u16 pbuf[8 * 16 * 40];
  __shared__ float lred[8][16];
  __shared__ float obuf[8][16][66];
  const int tid = threadIdx.x;
  const int w = tid >> 6, lane = tid & 63;
  const int lrow = lane & 15, quad = lane >> 4;
  const int blk = blockIdx.x;
  const int b = blk >> 7, q0 = (blk & 127) << 4;
  const u16* qp = qkv + (size_t)b * 2048 * 2304;
  const u16* kp = qp + 768;
  const int strip = w * 256;
  float* amrow = am + (size_t)b * 2048 * 2048 + (size_t)q0 * 2048;
  u16* ob = attnout + (size_t)b * 2048 * 768 + (size_t)q0 * 768;
  u16* pb = pbuf + w * 640;
  const float c12 = 1.f / 12.f;
  f32x4 zero = {0.f, 0.f, 0.f, 0.f};
  // head-mean accumulator: 4 rows x 16 cols per thread, summed over heads
  float amreg[4][16];
  #pragma unroll
  for (int r = 0; r < 4; r++)
    #pragma unroll
    for (int c = 0; c < 16; c++) amreg[r][c] = 0.f;
  for (int h = 0; h < 12; h++) {
    const u16* qh = qp + (size_t)(q0 + lrow) * 2304 + h * 64 + quad * 8;
    short8 qf0 = *(const short8*)qh;
    short8 qf1 = *(const short8*)(qh + 32);
    // ---- pass A: scores -> exp kept in regs, accumulate l per row ----
    f32x4 pex[16];
    float lsum[4] = {0.f, 0.f, 0.f, 0.f};
    #pragma unroll
    for (int t = 0; t < 16; t++) {
      const u16* kh = kp + (size_t)(strip + t * 16 + lrow) * 2304 + h * 64 + quad * 8;
      short8 kf0 = *(const short8*)kh;
      short8 kf1 = *(const short8*)(kh + 32);
      f32x4 sv = zero;
      sv = MFMA16(qf0, kf0, sv);
      sv = MFMA16(qf1, kf1, sv);
      f32x4 pe;
      #pragma unroll
      for (int r = 0; r < 4; r++) pe[r] = __expf(sv[r] * 0.125f);
      #pragma unroll
      for (int r = 0; r < 4; r++) lsum[r] += pe[r];
      pex[t] = pe;
    }
    #pragma unroll
    for (int o = 1; o < 16; o <<= 1)
      #pragma unroll
      for (int r = 0; r < 4; r++) lsum[r] += __shfl_xor(lsum[r], o);
    if (lrow == 0) {
      #pragma unroll
      for (int r = 0; r < 4; r++) lred[w][quad * 4 + r] = lsum[r];
    }
    __syncthreads();
    float invl[4];
    #pragma unroll
    for (int r = 0; r < 4; r++) {
      float s = 0.f;
      #pragma unroll
      for (int w2 = 0; w2 < 8; w2++) s += lred[w2][quad * 4 + r];
      invl[r] = 1.f / s;
    }
    // ---- pass C: normalize from regs, P@V ----
    f32x4 oacc[4];
    #pragma unroll
    for (int j = 0; j < 4; j++) oacc[j] = zero;
    const u16* vtp = VT + (size_t)(b * 12 + h) * 64 * 2048;
    #pragma unroll
    for (int c = 0; c < 8; c++) {
      const int cbase = strip + c * 32;
      short8 vf[4];
      #pragma unroll
      for (int j = 0; j < 4; j++)
        vf[j] = *(const short8*)(vtp + (size_t)(j * 16 + lrow) * 2048 + cbase + quad * 8);
      #pragma unroll
      for (int t2 = 0; t2 < 2; t2++) {
        #pragma unroll
        for (int r = 0; r < 4; r++) {
          float p = pex[c * 2 + t2][r] * invl[r];
          amreg[r][c * 2 + t2] += p;
          pb[(quad * 4 + r) * 40 + t2 * 16 + lrow] = f2bf(p);
        }
      }
      // cross-lane LDS RAW within the wave: pin order + completion
      asm volatile("s_waitcnt lgkmcnt(0)" ::: "memory");
      short8 pf = *(const short8*)(pb + lrow * 40 + quad * 8);
      #pragma unroll
      for (int j = 0; j < 4; j++) oacc[j] = MFMA16(pf, vf[j], oacc[j]);
      asm volatile("s_waitcnt lgkmcnt(0)" ::: "memory");
    }
    // ---- cross-wave output reduce in LDS, direct bf16 store ----
    #pragma unroll
    for (int j = 0; j < 4; j++)
      #pragma unroll
      for (int r = 0; r < 4; r++)
        obuf[w][quad * 4 + r][j * 16 + lrow] = oacc[j][r];
    __syncthreads();
    #pragma unroll
    for (int ee = 0; ee < 2; ee++) {
      int e = tid + ee * 512;
      int row = e >> 6, col = e & 63;
      float s = 0.f;
      #pragma unroll
      for (int w2 = 0; w2 < 8; w2++) s += obuf[w2][row][col];
      ob[(size_t)row * 768 + h * 64 + col] = f2bf(s);
    }
    __syncthreads();  // obuf + lred reuse next head
  }
  // ---- single head-mean write ----
  #pragma unroll
  for (int r = 0; r < 4; r++) {
    float* ar = amrow + (size_t)(quad * 4 + r) * 2048;
    #pragma unroll
    for (int c = 0; c < 8; c++) {
      ar[strip + c * 32 + lrow] = amreg[r][c * 2] * c12;
      ar[strip + c * 32 + 16 + lrow] = amreg[r][c * 2 + 1] * c12;
    }
  }
}

// ================= QK^T MFMA (node + cross) =================
__global__ __launch_bounds__(256) void qk_mfma(
    const u16* __restrict__ Q, int ldq, long qbs,
    const u16* __restrict__ Kp, int ldk, long kbs,
    float* __restrict__ S, long szs, int Sk, int nh, float scale) {
  __shared__ u16 Qs[128 * 72];
  __shared__ u16 Ks[128 * 72];
  const int tid = threadIdx.x;
  const int z = blockIdx.z, bb = z / nh, h = z - bb * nh;
  const u16* qp = Q + (size_t)bb * qbs + h * 64;
  const u16* kp = Kp + (size_t)bb * kbs + h * 64;
  float* sp = S + (size_t)z * szs;
  const int m0 = blockIdx.y * 128, n0 = blockIdx.x * 128;
  const int w = tid >> 6, lane = tid & 63;
  const int msub = (w & 1) * 64, nsub = (w >> 1) * 64;
  const int lrow = lane & 15, quad = lane >> 4;
  const int srow = tid >> 1, shalf = tid & 1;
  {
    const uint4* qg = (const uint4*)(qp + (size_t)(m0 + srow) * ldq + shalf * 32);
    const uint4* kg = (const uint4*)(kp + (size_t)(n0 + srow) * ldk + shalf * 32);
    uint4* qd = (uint4*)(Qs + srow * 72 + shalf * 32);
    uint4* kd = (uint4*)(Ks + srow * 72 + shalf * 32);
    #pragma unroll
    for (int u = 0; u < 4; u++) { qd[u] = qg[u]; kd[u] = kg[u]; }
  }
  __syncthreads();
  f32x4 zero = {0.f, 0.f, 0.f, 0.f};
  f32x4 acc[4][4];
  #pragma unroll
  for (int i = 0; i < 4; i++)
    #pragma unroll
    for (int j = 0; j < 4; j++) acc[i][j] = zero;
  #pragma unroll
  for (int ks = 0; ks < 2; ks++) {
    short8 af[4], bf[4];
    #pragma unroll
    for (int i = 0; i < 4; i++)
      af[i] = *(const short8*)(Qs + (msub + i * 16 + lrow) * 72 + ks * 32 + quad * 8);
    #pragma unroll
    for (int j = 0; j < 4; j++)
      bf[j] = *(const short8*)(Ks + (nsub + j * 16 + lrow) * 72 + ks * 32 + quad * 8);
    #pragma unroll
    for (int i = 0; i < 4; i++)
      #pragma unroll
      for (int j = 0; j < 4; j++)
        acc[i][j] = MFMA16(af[i], bf[j], acc[i][j]);
  }
  #pragma unroll
  for (int i = 0; i < 4; i++)
    #pragma unroll
    for (int j = 0; j < 4; j++) {
      int col = n0 + nsub + j * 16 + lrow;
      #pragma unroll
      for (int r = 0; r < 4; r++) {
        int row = m0 + msub + i * 16 + quad * 4 + r;
        sp[(size_t)row * Sk + col] = acc[i][j][r] * scale;
      }
    }
}

// ================= small softmax (Sk=128): node + cross; P->bf16 in place ==============
__global__ __launch_bounds__(128) void softmax_small(
    float* __restrict__ Sc, float* __restrict__ wout, int Sq) {
  const int q = blockIdx.x, b = blockIdx.y, tid = threadIdx.x;
  const int w = tid >> 6, lane = tid & 63;
  __shared__ float red[2];
  float am = 0.f;
  const size_t plane = (size_t)Sq * 128;
  for (int h = 0; h < 12; h++) {
    const int z = b * 12 + h;
    float* row = Sc + (size_t)z * plane + (size_t)q * 128;
    float v = row[tid];
    float m = wredmax(v);
    if (lane == 0) red[w] = m;
    __syncthreads();
    m = fmaxf(red[0], red[1]);
    float e = __expf(v - m);
    float s = wredsum(e);
    __syncthreads();
    if (lane == 0) red[w] = s;
    __syncthreads();
    float p = e / (red[0] + red[1]);
    ((u16*)(Sc + (size_t)z * plane))[(size_t)q * 256 + tid] = f2bf(p);
    am += p;
    __syncthreads();
  }
  wout[((size_t)b * Sq + q) * 128 + tid] = am * (1.f / 12.f);
}

// ================= small PV (Sk=128): Out[b, m, h*64+d] bf16, direct =================
__global__ __launch_bounds__(256) void pv_small(
    const u16* __restrict__ Pb, long pzs,
    const u16* __restrict__ KVb, int ldv, long vbs, int vhoff,
    u16* __restrict__ Outb, long obs) {
  __shared__ u16 Ps[128 * 40];
  __shared__ u16 Vs[64 * 40];
  const int tid = threadIdx.x;
  const int z = blockIdx.y, b = z / 12, h = z - b * 12;
  const u16* Pp = Pb + (size_t)z * pzs;
  const u16* Vp = KVb + (size_t)b * vbs + vhoff + h * 64;
  u16* Op = Outb + (size_t)b * obs + h * 64;
  const int m0 = blockIdx.x * 128;
  const int w = tid >> 6, lane = tid & 63;
  const int msub = w * 32;
  const int lrow = lane & 15, quad = lane >> 4;
  const int srow = tid >> 1, shalf = tid & 1;
  const int vk = tid >> 3, vn = (tid & 7) * 8;
  f32x4 zero = {0.f, 0.f, 0.f, 0.f};
  f32x4 acc[2][4];
  #pragma unroll
  for (int i = 0; i < 2; i++)
    #pragma unroll
    for (int j = 0; j < 4; j++) acc[i][j] = zero;
  #pragma unroll
  for (int k0 = 0; k0 < 128; k0 += 32) {
    uint4 pa = *(const uint4*)(Pp + (size_t)(m0 + srow) * 256 + k0 + shalf * 16);
    uint4 pb2 = *(const uint4*)(Pp + (size_t)(m0 + srow) * 256 + k0 + shalf * 16 + 8);
    uint4 vv = *(const uint4*)(Vp + (size_t)(k0 + vk) * ldv + vn);
    __syncthreads();
    *(uint4*)(Ps + srow * 40 + shalf * 16) = pa;
    *(uint4*)(Ps + srow * 40 + shalf * 16 + 8) = pb2;
    const u16* vs = (const u16*)&vv;
    #pragma unroll
    for (int u = 0; u < 8; u++) Vs[(vn + u) * 40 + vk] = vs[u];
    __syncthreads();
    short8 af[2], bf[4];
    #pragma unroll
    for (int i = 0; i < 2; i++)
      af[i] = *(const short8*)(Ps + (msub + i * 16 + lrow) * 40 + quad * 8);
    #pragma unroll
    for (int j = 0; j < 4; j++)
      bf[j] = *(const short8*)(Vs + (j * 16 + lrow) * 40 + quad * 8);
    #pragma unroll
    for (int i = 0; i < 2; i++)
      #pragma unroll
      for (int j = 0; j < 4; j++)
        acc[i][j] = MFMA16(af[i], bf[j], acc[i][j]);
  }
  #pragma unroll
  for (int i = 0; i < 2; i++)
    #pragma unroll
    for (int j = 0; j < 4; j++) {
      int col = j * 16 + lrow;
      #pragma unroll
      for (int r = 0; r < 4; r++) {
        int row = m0 + msub + i * 16 + quad * 4 + r;
        Op[(size_t)row * D_ + col] = f2bf(acc[i][j][r]);
      }
    }
}

// ================= LayerNorm of (x1 + x2) with optional bf16 twin =================
__global__ void ln_kernel(const float* __restrict__ x1, const float* __restrict__ x2,
                          const float* __restrict__ g, const float* __restrict__ bt,
                          float* __restrict__ outp, u16* __restrict__ outbf) {
  const int row = blockIdx.x;
  const int tid = threadIdx.x;
  __shared__ float red[8];
  float v[3];
  #pragma unroll
  for (int j = 0; j < 3; j++) {
    int c = tid + j * 256;
    v[j] = x1[(size_t)row * D_ + c] + x2[(size_t)row * D_ + c];
  }
  float s = v[0] + v[1] + v[2];
  s = wredsum(s);
  int wid = tid >> 6, lane = tid & 63;
  if (lane == 0) red[wid] = s;
  __syncthreads();
  float mean = (red[0] + red[1] + red[2] + red[3]) / 768.f;
  float d0 = v[0] - mean, d1 = v[1] - mean, d2 = v[2] - mean;
  float q = d0 * d0 + d1 * d1 + d2 * d2;
  q = wredsum(q);
  if (lane == 0) red[4 + wid] = q;
  __syncthreads();
  float var = (red[4] + red[5] + red[6] + red[7]) / 768.f;
  float inv = rsqrtf(var + 1e-5f);
  #pragma unroll
  for (int j = 0; j < 3; j++) {
    int c = tid + j * 256;
    float val = (v[j] - mean) * inv * g[c] + bt[c];
    outp[(size_t)row * D_ + c] = val;
    if (outbf) outbf[(size_t)row * D_ + c] = f2bf(val);
  }
}

// ================= w = mean over q of tok_attn (two-stage) =================
__global__ void colmean_part(const float* __restrict__ ta, float* __restrict__ part) {
  int b = blockIdx.y, z = blockIdx.z;
  int k = blockIdx.x * 256 + threadIdx.x;
  const float* p = ta + (size_t)b * S_ * S_ + (size_t)z * 256 * S_ + k;
  float s = 0.f;
  #pragma unroll 8
  for (int q = 0; q < 256; q++) s += p[(size_t)q * S_];
  part[((size_t)z * B_ + b) * S_ + k] = s;
}

__global__ void colmean_final(const float* __restrict__ part, float* __restrict__ w) {
  int b = blockIdx.y;
  int k = blockIdx.x * 256 + threadIdx.x;
  float s = 0.f;
  #pragma unroll
  for (int z = 0; z < 8; z++) s += part[((size_t)z * B_ + b) * S_ + k];
  w[b * S_ + k] = s * (1.f / (float)S_);
}

// ================= segment aggregation (seg sorted per batch) =================
__global__ void aggregate_kernel(const float* __restrict__ x, const float* __restrict__ w,
                                 const int* __restrict__ seg, float* __restrict__ outp,
                                 u16* __restrict__ outbf) {
  const int b = blockIdx.y, n = blockIdx.x;
  const int* sg = seg + b * S_;
  int l = 0, rr = S_;
  while (l < rr) { int mid = (l + rr) >> 1; if (sg[mid] < n) l = mid + 1; else rr = mid; }
  const int lo = l;
  rr = S_;
  while (l < rr) { int mid = (l + rr) >> 1; if (sg[mid] < n + 1) l = mid + 1; else rr = mid; }
  const int hi = l;
  const int tid = threadIdx.x;
  float acc[3] = {0.f, 0.f, 0.f};
  float den = 0.f;
  for (int s = lo; s < hi; s++) {
    float ww = w[b * S_ + s];
    den += ww;
    const float* xr = x + (size_t)(b * S_ + s) * D_;
    #pragma unroll
    for (int j = 0; j < 3; j++) acc[j] += ww * xr[tid + j * 256];
  }
  float invd = 1.f / (den + 1e-8f);
  size_t ro = (size_t)(b * N_ + n) * D_;
  #pragma unroll
  for (int j = 0; j < 3; j++) {
    float val = acc[j] * invd;
    outp[ro + tid + j * 256] = val;
    outbf[ro + tid + j * 256] = f2bf(val);
  }
}

// ================= enhanced = tokout + cross_proj + gather(node_emb), bf16 out ==========
__global__ void enhanced_kernel(const float* __restrict__ tokout, const float* __restrict__ crossp,
                                const float* __restrict__ nodeemb, const int* __restrict__ seg,
                                u16* __restrict__ outbf) {
  int g8 = blockIdx.x * 256 + threadIdx.x;
  int bs = g8 / 96, d0 = (g8 - bs * 96) * 8;
  int b = bs >> 11;
  int n = seg[bs];
  const float* t = tokout + (size_t)bs * D_ + d0;
  const float* cp = crossp + (size_t)bs * D_ + d0;
  const float* ne = nodeemb + (size_t)(b * N_ + n) * D_ + d0;
  float4 a0 = *(const float4*)t, a1 = *(const float4*)(t + 4);
  float4 b0 = *(const float4*)cp, b1 = *(const float4*)(cp + 4);
  float4 c0 = *(const float4*)ne, c1 = *(const float4*)(ne + 4);
  uint4 u;
  u.x = pk2(a0.x + b0.x + c0.x, a0.y + b0.y + c0.y);
  u.y = pk2(a0.z + b0.z + c0.z, a0.w + b0.w + c0.w);
  u.z = pk2(a1.x + b1.x + c1.x, a1.y + b1.y + c1.y);
  u.w = pk2(a1.z + b1.z + c1.z, a1.w + b1.w + c1.w);
  *(uint4*)(outbf + (size_t)g8 * 8) = u;
}

extern "C" void kernel_launch(void* const* d_in, const int* in_sizes, int n_in,
                              void* d_out, int out_size, void* d_ws, size_t ws_size,
                              hipStream_t stream) {
  const float* hs     = (const float*)d_in[0];
  const int*   t2s    = (const int*)d_in[1];
  const float* Wqkv_t = (const float*)d_in[2];
  const float* bqkv_t = (const float*)d_in[3];
  const float* Wo_t   = (const float*)d_in[4];
  const float* bo_t   = (const float*)d_in[5];
  const float* Wqkv_c = (const float*)d_in[6];
  const float* bqkv_c = (const float*)d_in[7];
  const float* Wo_c   = (const float*)d_in[8];
  const float* bo_c   = (const float*)d_in[9];
  const float* g_tok  = (const float*)d_in[10];
  const float* b_tok  = (const float*)d_in[11];
  const float* g_node = (const float*)d_in[12];
  const float* b_node = (const float*)d_in[13];
  const float* W_out  = (const float*)d_in[14];
  const float* b_out  = (const float*)d_in[15];

  float* ws = (float*)d_ws;
  // ---- workspace map (float offsets), phase-disjoint ----
  // R0 [0, 4,718,592)
  u16*   qkvbf       = (u16*)ws;                    // ph1-2
  u16*   enh_bf      = (u16*)ws;                    // ph7
  u16*   crossqbf    = (u16*)(ws + 1572864);        // ph5-6
  u16*   crossattn_bf= (u16*)(ws + 3145728);        // ph6-7
  // R1 [4,718,592, 13,107,200)
  float* R1 = ws + 4718592;
  u16*   hs_bf   = (u16*)R1;                        // ph1 (dead after QKV)
  u16*   wqkvt1  = (u16*)(R1 + 1572864);            // ph1
  u16*   VT      = (u16*)R1;                        // ph2: 3,145,728 u16 (overwrites hs_bf)
  float* projbuf = R1;                              // ph3
  float* Snode   = R1;                              // ph4 (393,216)
  u16*   wqkvt2  = (u16*)(R1 + 4000000);            // ph4
  u16*   wot     = (u16*)(R1 + 6291456);            // ph3-4
  u16*   wqkvc   = (u16*)R1;                        // ph5
  u16*   woc     = (u16*)(R1 + 6291456);            // ph5-7
  u16*   wout    = (u16*)(R1 + 6586368);            // ph5-7
  float* Scross  = R1;                              // ph6 (6,291,456)
  float* crossproj = R1;                            // ph7
  // R2 [13,107,200, 16,252,928)
  float* R2 = ws + 13107200;
  u16*   attnout_bf = (u16*)R2;                     // ph2-3a (bf16 attn out, direct)
  u16*   tokout_bf  = (u16*)R2;                     // ph3b-5 (after gemm ph3 consumed attnout)
  float* wvec       = R2 + 1572864;
  float* colpart    = R2 + 1576960;
  float* nodepre    = R2 + 1609728;
  float* nodeproj   = R2 + 1806336;
  u16*   nodepre_bf = (u16*)(R2 + 2002944);
  u16*   nodeattn_bf= (u16*)(R2 + 2101248);
  u16*   nodeemb_bf = (u16*)(R2 + 2199552);
  u16*   nodeqkvbf  = (u16*)(R2 + 2297856);
  u16*   crosskvbf  = (u16*)(R2 + 2592768);
  // R3
  float* tokout = ws + 16252928;

  float* outp       = (float*)d_out;
  float* o_output   = outp;
  float* o_nodeemb  = outp + 3145728;
  float* o_tokattn  = o_nodeemb + 196608;
  float* o_nodeattn = o_tokattn + 8388608;
  float* o_crossw   = o_nodeattn + 32768;

  // ---- ph1: convert + token QKV ----
  conv_bf16<<<1536, 256, 0, stream>>>(hs, hs_bf, 393216);
  conv_bf16<<<864, 256, 0, stream>>>(Wqkv_t, wqkvt1, 221184);
  gemm_bf16<1><<<dim3(18, 32), 256, 0, stream>>>(hs_bf, 768, wqkvt1, 768, bqkv_t, qkvbf, 2304, 768);

  // ---- ph2: fused token self-attention (bf16 out, no atomics) ----
  transpose_v<<<dim3(32, 24), 256, 0, stream>>>(qkvbf, VT);
  fused_tok_attn<<<256, 512, 0, stream>>>(qkvbf, VT, o_tokattn, attnout_bf);

  // ---- ph3: token out projection + LN ----
  conv_bf16<<<288, 256, 0, stream>>>(Wo_t, wot, 73728);
  gemm_bf16<0><<<dim3(6, 32), 256, 0, stream>>>(attnout_bf, 768, wot, 768, bo_t, projbuf, 768, 768);
  ln_kernel<<<4096, 256, 0, stream>>>(hs, projbuf, g_tok, b_tok, tokout, tokout_bf);

  // ---- ph4: token->node aggregation + node attention ----
  colmean_part<<<dim3(8, 2, 8), 256, 0, stream>>>(o_tokattn, colpart);
  colmean_final<<<dim3(8, 2), 256, 0, stream>>>(colpart, wvec);
  aggregate_kernel<<<dim3(128, 2), 256, 0, stream>>>(tokout, wvec, t2s, nodepre, nodepre_bf);
  conv_bf16<<<864, 256, 0, stream>>>(Wqkv_t, wqkvt2, 221184);
  gemm_bf16<1><<<dim3(18, 2), 256, 0, stream>>>(nodepre_bf, 768, wqkvt2, 768, bqkv_t, nodeqkvbf, 2304, 768);
  qk_mfma<<<dim3(1, 1, 24), 256, 0, stream>>>(
      nodeqkvbf, 2304, (long)128 * 2304, nodeqkvbf + 768, 2304, (long)128 * 2304,
      Snode, 16384, 128, 12, 0.125f);
  softmax_small<<<dim3(128, 2), 128, 0, stream>>>(Snode, o_nodeattn, 128);
  pv_small<<<dim3(1, 24), 256, 0, stream>>>(
      (const u16*)Snode, 32768, nodeqkvbf, 2304, (long)128 * 2304, 1536,
      nodeattn_bf, (long)128 * 768);
  gemm_bf16<0><<<dim3(6, 2), 256, 0, stream>>>(nodeattn_bf, 768, wot, 768, bo_t, nodeproj, 768, 768);
  ln_kernel<<<256, 256, 0, stream>>>(nodepre, nodeproj, g_node, b_node, o_nodeemb, nodeemb_bf);

  // ---- ph5: cross projections ----
  conv_bf16<<<864, 256, 0, stream>>>(Wqkv_c, wqkvc, 221184);
  conv_bf16<<<288, 256, 0, stream>>>(Wo_c, woc, 73728);
  conv_bf16<<<288, 256, 0, stream>>>(W_out, wout, 73728);
  gemm_bf16<1><<<dim3(6, 32), 256, 0, stream>>>(tokout_bf, 768, wqkvc, 768, bqkv_c, crossqbf, 768, 768);
  gemm_bf16<1><<<dim3(12, 2), 256, 0, stream>>>(nodeemb_bf, 768, wqkvc + 768 * 768, 768, bqkv_c + 768,
                                                crosskvbf, 1536, 768);

  // ---- ph6: cross attention (24 planes) ----
  qk_mfma<<<dim3(1, 16, 24), 256, 0, stream>>>(
      crossqbf, 768, (long)2048 * 768, crosskvbf, 1536, (long)128 * 1536,
      Scross, 262144, 128, 12, 0.125f);
  softmax_small<<<dim3(2048, 2), 128, 0, stream>>>(Scross, o_crossw, 2048);
  pv_small<<<dim3(16, 24), 256, 0, stream>>>(
      (const u16*)Scross, 524288, crosskvbf, 1536, (long)128 * 1536, 768,
      crossattn_bf, (long)2048 * 768);

  // ---- ph7: cross out projection, combine, final ----
  gemm_bf16<0><<<dim3(6, 32), 256, 0, stream>>>(crossattn_bf, 768, woc, 768, bo_c, crossproj, 768, 768);
  enhanced_kernel<<<1536, 256, 0, stream>>>(tokout, crossproj, o_nodeemb, t2s, enh_bf);
  gemm_bf16<0><<<dim3(6, 32), 256, 0, stream>>>(enh_bf, 768, wout, 768, b_out, o_output, 768, 768);
}